// Round 8
// baseline (17674.318 us; speedup 1.0000x reference)
//
#include <hip/hip_runtime.h>
#include <math.h>

#define SS 512
#define BB 64
#define EE 256
#define HH 512
#define NT 9
#define NWG 256

// ws layout (float32 elements):
//  hp   : packed h, SS*8bg*32slice*128 at 0   (block = [bb][u], 16u x 8bb)
//  em   : SS*BB*NT at EM_OFF
//  num  : 64 at NUM_OFF
//  norm : 64 at NORM_OFF
//  flags: SS*8*32 u32 at FLAG_OFF   (one u32 per (t, bg, slice))
#define HP_ELEMS ((size_t)SS * 8 * 32 * 128)
#define EM_OFF   HP_ELEMS
#define NUM_OFF  (EM_OFF + (size_t)SS * BB * NT)
#define NORM_OFF (NUM_OFF + 64)
#define FLAG_OFF (NORM_OFF + 64)
#define FLAG_U32S ((size_t)SS * 8 * 32)

// dynamic LDS layout (floats)
#define L_WIH 0                  // 64 rows x 256 (x16-prescaled)  = 16384
#define L_HL  16384              // 8 x 520                        = 4160
#define L_GH  20544              // gsm_hh 64 x 9                  = 576
#define L_GI  21120              // gsm_ih 64 x 9                  = 576
#define L_CS  21696              // c-state 16 x 8                 = 128
#define L_TOT 21824              // 87296 bytes

__global__ __launch_bounds__(256) void init_flags(float* __restrict__ ws) {
    unsigned* f = (unsigned*)(ws + FLAG_OFF);
    size_t idx = (size_t)blockIdx.x * 256 + threadIdx.x;
    if (idx < FLAG_U32S) f[idx] = 0u;
}

// Persistent LSTM: 256 WGs x 512 threads (slice = wg&31, bg = wg>>5).
// Wave w: gate-rows w*8..w*8+7.  Lane L: hh k-chunk [8L,8L+8), ih k-chunk [4L,4L+4).
// Whh in REGISTERS whh[8][8]=64; acc[16] (8 rows x 2 batches, 4 passes) keeps
// peak ~110 VGPR < 128 cap (R5-R7 spilled with acc[64]+wih).
// Wih in LDS (staged once, x16-prescaled).  ih gates go through gsm_ih.
// Sync-v2: packed h blocks + per-slice data flags; all waves poll the 32-flag
// line directly (no atomic-add chain, no tid0-spin broadcast).
__global__ __launch_bounds__(512) void lstm_persistent(
    const float* __restrict__ Whh, const float* __restrict__ Wih,
    const float* __restrict__ bih, const float* __restrict__ bhh,
    const float* __restrict__ emb, const int* __restrict__ x,
    float* __restrict__ ws)
{
    const int wg    = blockIdx.x;
    const int slice = wg & 31;
    const int bg    = wg >> 5;
    const int tid   = threadIdx.x;
    const int w     = tid >> 6;
    const int L     = tid & 63;
    const int bbase = bg * 8;

    float* hp = ws;
    unsigned* flags = (unsigned*)(ws + FLAG_OFF);

    extern __shared__ float smem[];
    float* wih_l = smem + L_WIH;
    float* h_l   = smem + L_HL;    // [b_l][520]
    float* gh    = smem + L_GH;    // gsm_hh [row][9]
    float* gi    = smem + L_GI;    // gsm_ih [row][9]
    float* cs_l  = smem + L_CS;    // [u][8]

    // ---- Whh into registers: 8 rows x k-chunk [8L, 8L+8) ----
    float whh[8][8];
#pragma unroll
    for (int r = 0; r < 8; r++) {
        int l  = w * 8 + r;
        int gr = (l >> 4) * HH + slice * 16 + (l & 15);
        float4 a0 = *(const float4*)(Whh + (size_t)gr * HH + 8 * L);
        float4 a1 = *(const float4*)(Whh + (size_t)gr * HH + 8 * L + 4);
        whh[r][0] = a0.x; whh[r][1] = a0.y; whh[r][2] = a0.z; whh[r][3] = a0.w;
        whh[r][4] = a1.x; whh[r][5] = a1.y; whh[r][6] = a1.z; whh[r][7] = a1.w;
    }

    // ---- stage Wih slice into LDS (x16 prescale = sqrt(E) folding) ----
    for (int i = 0; i < 32; i++) {
        int idx = i * 512 + tid;          // row*256 + k
        int row = idx >> 8, k = idx & 255;
        int gr = (row >> 4) * HH + slice * 16 + (row & 15);
        wih_l[idx] = Wih[(size_t)gr * EE + k] * 16.0f;
    }

    // bias preload (activation threads)
    float bs0 = 0.f, bs1 = 0.f, bs2 = 0.f, bs3 = 0.f;
    if (tid < 128) {
        const int u  = tid & 15;
        const int bb = tid >> 4;
        const int gu = slice * 16 + u;
        bs0 = bih[0 * HH + gu] + bhh[0 * HH + gu];
        bs1 = bih[1 * HH + gu] + bhh[1 * HH + gu];
        bs2 = bih[2 * HH + gu] + bhh[2 * HH + gu];
        bs3 = bih[3 * HH + gu] + bhh[3 * HH + gu];
        cs_l[u * 8 + bb] = 0.0f;
    }

    // h_{-1} = 0
#pragma unroll
    for (int j = 0; j < 8; j++) {
        int idx = j * 512 + tid;               // b*512 + k
        h_l[(idx >> 9) * 520 + (idx & 511)] = 0.0f;
    }
    __syncthreads();   // wih_l / h_l / cs_l ready

    // ================= helpers as macros (keep indices static) =============
    // butterfly over acc[16]: lane ends with full sum of value (L&15)
#define BFLY16()                                                          \
    _Pragma("unroll")                                                     \
    for (int d = 3; d >= 0; d--) {                                        \
        const int  m    = 1 << d;                                         \
        const int  half = 1 << d;                                         \
        const bool up   = (L & m) != 0;                                   \
        _Pragma("unroll")                                                 \
        for (int i = 0; i < half; i++) {                                  \
            float send = up ? acc[i] : acc[i + half];                     \
            float recv = __shfl_xor(send, m, 64);                         \
            acc[i] = (up ? acc[i + half] : acc[i]) + recv;                \
        }                                                                 \
    }                                                                     \
    acc[0] += __shfl_xor(acc[0], 16, 64);                                 \
    acc[0] += __shfl_xor(acc[0], 32, 64);

    // ih gates for step tt -> gsm_ih (4 passes x 2 batches), k = 4L..4L+4
#define IH_PASSES(tt)                                                     \
    _Pragma("unroll")                                                     \
    for (int p = 0; p < 4; p++) {                                         \
        float acc[16];                                                    \
        _Pragma("unroll")                                                 \
        for (int bb = 0; bb < 2; bb++) {                                  \
            int xv = x[(tt) * BB + bbase + p * 2 + bb];                   \
            float4 e4 = *(const float4*)(emb + (size_t)xv * EE + 4 * L);  \
            _Pragma("unroll")                                             \
            for (int r = 0; r < 8; r++) {                                 \
                float4 w4 = *(const float4*)(wih_l + r * 256 + 64 * w * 0 + 4 * L); \
                w4 = *(const float4*)(wih_l + (w * 8 + r) * 256 + 4 * L); \
                float v = w4.x * e4.x + w4.y * e4.y + w4.z * e4.z + w4.w * e4.w; \
                acc[r * 2 + bb] = (bb == 0) ? ((void)0, v) : v;           \
                if (bb == 0) acc[r * 2 + 1] = 0.0f;                       \
                acc[r * 2 + bb] = v;                                      \
            }                                                             \
        }                                                                 \
        BFLY16();                                                         \
        if (L < 16) gi[(w * 8 + ((L & 15) >> 1)) * 9 + p * 2 + (L & 1)] = acc[0]; \
    }

    // ---- ih(0) ----
    IH_PASSES(0);
    __syncthreads();

    for (int t = 0; t < SS; t++) {
        // ---- hh gates: 4 passes x 2 batches, whh regs x h_l ----
#pragma unroll
        for (int p = 0; p < 4; p++) {
            float acc[16];
#pragma unroll
            for (int bb = 0; bb < 2; bb++) {
                const float* hrow = h_l + (p * 2 + bb) * 520;
                float4 h0 = *(const float4*)(hrow + 8 * L);
                float4 h1 = *(const float4*)(hrow + 8 * L + 4);
#pragma unroll
                for (int r = 0; r < 8; r++) {
                    acc[r * 2 + bb] = whh[r][0] * h0.x + whh[r][1] * h0.y +
                                      whh[r][2] * h0.z + whh[r][3] * h0.w +
                                      whh[r][4] * h1.x + whh[r][5] * h1.y +
                                      whh[r][6] * h1.z + whh[r][7] * h1.w;
                }
            }
            BFLY16();
            if (L < 16) gh[(w * 8 + ((L & 15) >> 1)) * 9 + p * 2 + (L & 1)] = acc[0];
        }
        __syncthreads();

        // ---- activations + state update + packed h store ----
        if (tid < 128) {
            const int u  = tid & 15;
            const int bb = tid >> 4;
            float g0 = gh[(0 * 16 + u) * 9 + bb] + gi[(0 * 16 + u) * 9 + bb] + bs0;
            float g1 = gh[(1 * 16 + u) * 9 + bb] + gi[(1 * 16 + u) * 9 + bb] + bs1;
            float g2 = gh[(2 * 16 + u) * 9 + bb] + gi[(2 * 16 + u) * 9 + bb] + bs2;
            float g3 = gh[(3 * 16 + u) * 9 + bb] + gi[(3 * 16 + u) * 9 + bb] + bs3;
            float i_ = 1.0f / (1.0f + expf(-g0));
            float f_ = 1.0f / (1.0f + expf(-g1));
            float o_ = 1.0f / (1.0f + expf(-g3));
            float cn = f_ * cs_l[u * 8 + bb] + i_ * tanhf(g2);
            float hn = o_ * tanhf(cn);
            cs_l[u * 8 + bb] = cn;
            __hip_atomic_store(
                &hp[(((size_t)t * 8 + bg) * 32 + slice) * 128 + tid],
                hn, __ATOMIC_RELAXED, __HIP_MEMORY_SCOPE_AGENT);
        }
        __syncthreads();   // vmcnt(0) drained for activation waves

        // ---- publish per-slice flag (data already at LLC) ----
        if (tid == 0) {
            __hip_atomic_store(&flags[((size_t)t * 8 + bg) * 32 + slice], 1u,
                               __ATOMIC_RELAXED, __HIP_MEMORY_SCOPE_AGENT);
        }

        if (t + 1 < SS) {
            // ---- ih(t+1) overlapped before the poll ----
            IH_PASSES(t + 1);

            // ---- all waves poll the 32-flag line for (t, bg) ----
            {
                const unsigned* fl = flags + ((size_t)t * 8 + bg) * 32;
                for (;;) {
                    unsigned v = 1u;
                    if (L < 32)
                        v = __hip_atomic_load(&fl[L], __ATOMIC_RELAXED,
                                              __HIP_MEMORY_SCOPE_AGENT);
                    if (__all(v != 0u)) break;
                }
            }

            // ---- stage h_t: packed blocks -> h_l[b][k] ----
            const float* hsrc = hp + ((size_t)t * 8 + bg) * 32 * 128;
#pragma unroll
            for (int j = 0; j < 8; j++) {
                int idx = j * 512 + tid;        // s*128 + (bb*16+u), contiguous
                float v = __hip_atomic_load(&hsrc[idx], __ATOMIC_RELAXED,
                                            __HIP_MEMORY_SCOPE_AGENT);
                int jj = idx & 127;
                h_l[(jj >> 4) * 520 + (idx >> 7) * 16 + (jj & 15)] = v;
            }
            __syncthreads();
        }
    }
}

// one wave per (t,b): logits = h @ W_out^T + b_out, then log_softmax
__global__ __launch_bounds__(256) void emis_kernel(
    const float* __restrict__ Wout, const float* __restrict__ bout,
    float* __restrict__ ws)
{
    int wid = blockIdx.x * 4 + (threadIdx.x >> 6);  // t*64 + b
    int L   = threadIdx.x & 63;
    int t = wid >> 6, b = wid & 63;
    const float* hb = ws + ((size_t)t * 8 + (b >> 3)) * 32 * 128;
    const int bb = b & 7;
    float hv[8];
#pragma unroll
    for (int i = 0; i < 8; i++)   // k = i*64 + L
        hv[i] = hb[(size_t)(i * 4 + (L >> 4)) * 128 + bb * 16 + (L & 15)];
    float acc[9];
#pragma unroll
    for (int tg = 0; tg < 9; tg++) acc[tg] = 0.0f;
    for (int i = 0; i < 8; i++) {
#pragma unroll
        for (int tg = 0; tg < 9; tg++)
            acc[tg] += Wout[tg * HH + i * 64 + L] * hv[i];
    }
#pragma unroll
    for (int tg = 0; tg < 9; tg++) {
        acc[tg] += __shfl_xor(acc[tg], 1, 64);
        acc[tg] += __shfl_xor(acc[tg], 2, 64);
        acc[tg] += __shfl_xor(acc[tg], 4, 64);
        acc[tg] += __shfl_xor(acc[tg], 8, 64);
        acc[tg] += __shfl_xor(acc[tg], 16, 64);
        acc[tg] += __shfl_xor(acc[tg], 32, 64);
    }
    float lg[9];
#pragma unroll
    for (int tg = 0; tg < 9; tg++) lg[tg] = acc[tg] + bout[tg];
    float m = lg[0];
#pragma unroll
    for (int tg = 1; tg < 9; tg++) m = fmaxf(m, lg[tg]);
    float ssum = 0.0f;
#pragma unroll
    for (int tg = 0; tg < 9; tg++) ssum += expf(lg[tg] - m);
    float lse = m + logf(ssum);
    float myo = lg[0] - lse;
#pragma unroll
    for (int tg = 1; tg < 9; tg++) if (L == tg) myo = lg[tg] - lse;
    if (L < 9) ws[EM_OFF + (size_t)wid * 9 + L] = myo;
}

// merged CRF: blocks 0..7 numerator, 8..15 forward(logZ), 16..23 viterbi
__global__ __launch_bounds__(512) void crf_all(
    const int* __restrict__ x, const int* __restrict__ bio,
    const float* __restrict__ start_t, const float* __restrict__ end_t,
    const float* __restrict__ trans, float* __restrict__ ws,
    float* __restrict__ out)
{
    const float* em = ws + EM_OFF;
    const int role  = blockIdx.x >> 3;
    const int local = blockIdx.x & 7;
    const int tid   = threadIdx.x;

    __shared__ float sc[9][8];
    __shared__ unsigned char hist[SS - 1][8][9];

    if (role == 0) {
        int b = local * 8 + (tid >> 6);
        int L = tid & 63;
        float sum = 0.0f;
        int cntm = 0;
#pragma unroll
        for (int j = 0; j < 8; j++) {
            int s = j * 64 + L;
            int tg = bio[s * BB + b];
            bool mk = (x[s * BB + b] != 0);
            cntm += mk ? 1 : 0;
            if (s == 0) {
                sum += start_t[tg] + em[(size_t)b * 9 + tg];
            } else if (mk) {
                int tp = bio[(s - 1) * BB + b];
                sum += em[((size_t)s * BB + b) * 9 + tg] + trans[tp * 9 + tg];
            }
        }
#pragma unroll
        for (int d = 1; d < 64; d <<= 1) {
            sum += __shfl_xor(sum, d, 64);
            cntm += __shfl_xor(cntm, d, 64);
        }
        if (L == 0) {
            int se = cntm - 1;
            sum += end_t[bio[se * BB + b]];
            ws[NUM_OFF + b] = sum;
        }
        return;
    }

    const int b_l = tid & 7;
    const int j   = tid >> 3;          // active j < 9
    const int b   = local * 8 + b_l;
    float tc[9];
    if (j < 9) {
#pragma unroll
        for (int i = 0; i < 9; i++) tc[i] = trans[i * 9 + j];
        sc[j][b_l] = start_t[j] + em[(size_t)b * 9 + j];
    }
    __syncthreads();

    if (role == 1) {
        for (int s = 1; s < SS; s++) {
            float nv = 0.0f;
            if (j < 9) {
                float sv[9];
                float m = -3.4e38f;
#pragma unroll
                for (int i = 0; i < 9; i++) {
                    sv[i] = sc[i][b_l] + tc[i];
                    m = fmaxf(m, sv[i]);
                }
                float ssum = 0.0f;
#pragma unroll
                for (int i = 0; i < 9; i++) ssum += expf(sv[i] - m);
                nv = m + logf(ssum) + em[((size_t)s * BB + b) * 9 + j];
            }
            bool mk = (x[s * BB + b] != 0);
            __syncthreads();
            if (j < 9 && mk) sc[j][b_l] = nv;
            __syncthreads();
        }
        if (j == 0) {
            float m = -3.4e38f;
#pragma unroll
            for (int i = 0; i < 9; i++) m = fmaxf(m, sc[i][b_l] + end_t[i]);
            float ssum = 0.0f;
#pragma unroll
            for (int i = 0; i < 9; i++) ssum += expf(sc[i][b_l] + end_t[i] - m);
            ws[NORM_OFF + b] = m + logf(ssum);
        }
    } else {
        for (int s = 1; s < SS; s++) {
            float nv = 0.0f;
            if (j < 9) {
                float best = sc[0][b_l] + tc[0];
                int bi = 0;
#pragma unroll
                for (int i = 1; i < 9; i++) {
                    float v = sc[i][b_l] + tc[i];
                    if (v > best) { best = v; bi = i; }  // first-max = jnp.argmax
                }
                hist[s - 1][b_l][j] = (unsigned char)bi;
                nv = best + em[((size_t)s * BB + b) * 9 + j];
            }
            __syncthreads();
            if (j < 9) sc[j][b_l] = nv;
            __syncthreads();
        }
        if (tid < 8) {
            int bl = tid;
            int gb = local * 8 + bl;
            float best = sc[0][bl] + end_t[0];
            int cur = 0;
#pragma unroll
            for (int i = 1; i < 9; i++) {
                float v = sc[i][bl] + end_t[i];
                if (v > best) { best = v; cur = i; }
            }
            out[1 + (size_t)(SS - 1) * BB + gb] = (float)cur;
            for (int s = SS - 2; s >= 0; s--) {
                cur = hist[s][bl][cur];
                out[1 + (size_t)s * BB + gb] = (float)cur;
            }
        }
    }
}

__global__ __launch_bounds__(64) void final_llh(const float* __restrict__ ws,
                                               float* __restrict__ out)
{
    int L = threadIdx.x;
    float v = ws[NUM_OFF + L] - ws[NORM_OFF + L];
    v += __shfl_xor(v, 1, 64);
    v += __shfl_xor(v, 2, 64);
    v += __shfl_xor(v, 4, 64);
    v += __shfl_xor(v, 8, 64);
    v += __shfl_xor(v, 16, 64);
    v += __shfl_xor(v, 32, 64);
    if (L == 0) out[0] = -v;
}

extern "C" void kernel_launch(void* const* d_in, const int* in_sizes, int n_in,
                              void* d_out, int out_size, void* d_ws, size_t ws_size,
                              hipStream_t stream) {
    const int*   x       = (const int*)d_in[0];
    const int*   bio     = (const int*)d_in[1];
    const float* emb     = (const float*)d_in[2];
    const float* W_ih    = (const float*)d_in[3];
    const float* W_hh    = (const float*)d_in[4];
    const float* b_ih    = (const float*)d_in[5];
    const float* b_hh    = (const float*)d_in[6];
    const float* W_out   = (const float*)d_in[7];
    const float* b_out   = (const float*)d_in[8];
    const float* start_t = (const float*)d_in[9];
    const float* end_t   = (const float*)d_in[10];
    const float* trans   = (const float*)d_in[11];
    float* out = (float*)d_out;
    float* ws  = (float*)d_ws;

    const size_t dyn_lds = (size_t)L_TOT * sizeof(float);   // 87296 B
    hipFuncSetAttribute((const void*)lstm_persistent,
                        hipFuncAttributeMaxDynamicSharedMemorySize,
                        (int)dyn_lds);

    init_flags<<<512, 256, 0, stream>>>(ws);
    lstm_persistent<<<NWG, 512, dyn_lds, stream>>>(W_hh, W_ih, b_ih, b_hh, emb, x, ws);
    emis_kernel<<<SS * BB / 4, 256, 0, stream>>>(W_out, b_out, ws);
    crf_all<<<24, 512, 0, stream>>>(x, bio, start_t, end_t, trans, ws, out);
    final_llh<<<1, 64, 0, stream>>>(ws, out);
}

// Round 9
// 11615.916 us; speedup vs baseline: 1.5216x; 1.5216x over previous
//
#include <hip/hip_runtime.h>
#include <math.h>

#define SS 512
#define BB 64
#define EE 256
#define HH 512
#define NT 9
#define NWG 256

// ws layout (float32 elements):
//  hp   : packed h, SS*4bgr*64rg*128 at 0   (block = [bb(16)][u(8)])
//  em   : SS*BB*NT at EM_OFF
//  num  : 64 at NUM_OFF
//  norm : 64 at NORM_OFF
//  flags: SS*4*64 u32 at FLAG_OFF  (flag per (t, bgr, rg), 64-u32 line per (t,bgr))
#define HP_ELEMS ((size_t)SS * 4 * 64 * 128)
#define EM_OFF   HP_ELEMS
#define NUM_OFF  (EM_OFF + (size_t)SS * BB * NT)
#define NORM_OFF (NUM_OFF + 64)
#define FLAG_OFF (NORM_OFF + 64)
#define FLAG_U32S ((size_t)SS * 4 * 64)

// dynamic LDS layout (floats)
#define L_WHH 0            // 32 rows x 512            = 16384 (64 KB)
#define L_HL  16384        // 2 halves x 8 x 520       = 8320
#define L_GSM 24704        // 32 x 17                  = 544
#define L_CS  25248        // 8u x 16b                 = 128
#define L_TOT 25376        // 101504 bytes

__global__ __launch_bounds__(256) void init_flags(float* __restrict__ ws) {
    unsigned* f = (unsigned*)(ws + FLAG_OFF);
    size_t idx = (size_t)blockIdx.x * 256 + threadIdx.x;
    if (idx < FLAG_U32S) f[idx] = 0u;
}

// Persistent LSTM: 256 WGs x 512 thr. WG = (rg = wg&63: 8 units x 4 gates = 32
// gate-rows) x (bgr = wg>>6: 16 batches). Row l (0..31): gate = l>>3,
// unit_local = l&7, global row = (l>>3)*512 + rg*8 + (l&7).
// Wave w: rows w*4..w*4+3. Lane L: kc = L>>3 (k-chunk 4 floats), b_l = L&7.
// vs R4 (64 rows x 8 batches): each Whh b128 LDS read now serves 2 batch-
// halves -> weight reads 128->64 per wave per step (the dominant LDS term).
// Reduction = R4's 3-round shfl_xor(8,16,32) allreduce over kc (24 shuffles).
// Barrier: producer flag store + wave0 64-lane poll (no atomic RMW chain).
// Cross-WG h via RELAXED agent atomics (LLC-coherent, no invalidations).
__global__ __launch_bounds__(512) void lstm_persistent(
    const float* __restrict__ Whh, const float* __restrict__ Wih,
    const float* __restrict__ bih, const float* __restrict__ bhh,
    const float* __restrict__ emb, const int* __restrict__ x,
    float* __restrict__ ws)
{
    const int wg  = blockIdx.x;
    const int rg  = wg & 63;
    const int bgr = wg >> 6;
    const int tid = threadIdx.x;
    const int w   = tid >> 6;
    const int L   = tid & 63;
    const int b_l = L & 7;
    const int kc  = L >> 3;

    float* hp = ws;
    unsigned* flags = (unsigned*)(ws + FLAG_OFF);

    extern __shared__ float smem[];
    float* whh_l = smem + L_WHH;   // [l(32)][512]
    float* h_l   = smem + L_HL;    // [bh(2)][b_l(8)][520]
    float* gsm   = smem + L_GSM;   // [l(32)][17]
    float* cs_l  = smem + L_CS;    // [u(8)][16]

    // ---- stage Whh slice (32 rows x 512) into LDS, coalesced ----
    for (int i = 0; i < 32; i++) {
        int idx = i * 512 + tid;          // l*512 + k
        int l = idx >> 9, k = idx & 511;
        int gr = (l >> 3) * HH + rg * 8 + (l & 7);
        whh_l[idx] = Whh[(size_t)gr * HH + k];
    }

    // bias preload (activation threads: u = tid&7, bb = tid>>3)
    float bs0 = 0.f, bs1 = 0.f, bs2 = 0.f, bs3 = 0.f;
    if (tid < 128) {
        const int u  = tid & 7;
        const int bb = tid >> 3;
        const int gu = rg * 8 + u;
        bs0 = bih[0 * HH + gu] + bhh[0 * HH + gu];
        bs1 = bih[1 * HH + gu] + bhh[1 * HH + gu];
        bs2 = bih[2 * HH + gu] + bhh[2 * HH + gu];
        bs3 = bih[3 * HH + gu] + bhh[3 * HH + gu];
        cs_l[u * 16 + bb] = 0.0f;
    }

    // h_{-1} = 0 (both batch-halves incl. padding)
    for (int i = 0; i < 17; i++) {
        int idx = i * 512 + tid;
        if (idx < 8320) h_l[idx] = 0.0f;
    }

    // row bases for ih (global Wih)
    int grow[4];
#pragma unroll
    for (int r = 0; r < 4; r++) {
        int l = w * 4 + r;
        grow[r] = (l >> 3) * HH + rg * 8 + (l & 7);
    }

    // ---- ih gates for t=0: acc_ih[r*2+bh] ----
    float acc_ih[8];
#pragma unroll
    for (int i = 0; i < 8; i++) acc_ih[i] = 0.0f;
#pragma unroll
    for (int bh = 0; bh < 2; bh++) {
        int xv = x[0 * BB + bgr * 16 + bh * 8 + b_l];
        const float* erow = emb + (size_t)xv * EE;
        for (int c = 0; c < 8; c++) {
            const int k0 = c * 32 + kc * 4;
            float4 e4 = *(const float4*)(erow + k0);
            e4.x *= 16.0f; e4.y *= 16.0f; e4.z *= 16.0f; e4.w *= 16.0f;
#pragma unroll
            for (int r = 0; r < 4; r++) {
                float4 w4 = *(const float4*)(Wih + (size_t)grow[r] * EE + k0);
                acc_ih[r * 2 + bh] += w4.x * e4.x + w4.y * e4.y +
                                      w4.z * e4.z + w4.w * e4.w;
            }
        }
    }
    __syncthreads();

    const float* wbase = whh_l + (size_t)(w * 4) * 512;

    for (int t = 0; t < SS; t++) {
        // ---- hh gates: acc[r*2+bh] += whh row . h[bh][b_l] (w4 reused 2x) ----
        float acc[8];
#pragma unroll
        for (int i = 0; i < 8; i++) acc[i] = acc_ih[i];
        const float* hra = h_l + b_l * 520;
        const float* hrb = h_l + 4160 + b_l * 520;
        for (int c = 0; c < 16; c++) {
            const int k0 = c * 32 + kc * 4;
            float4 ha = *(const float4*)(hra + k0);
            float4 hb = *(const float4*)(hrb + k0);
#pragma unroll
            for (int r = 0; r < 4; r++) {
                float4 w4 = *(const float4*)(wbase + r * 512 + k0);
                acc[r * 2 + 0] += w4.x * ha.x + w4.y * ha.y +
                                  w4.z * ha.z + w4.w * ha.w;
                acc[r * 2 + 1] += w4.x * hb.x + w4.y * hb.y +
                                  w4.z * hb.z + w4.w * hb.w;
            }
        }

        // ---- reduce over 8 kc-lanes (lane bits 3,4,5), R4-proven ----
#pragma unroll
        for (int i = 0; i < 8; i++) {
            acc[i] += __shfl_xor(acc[i], 8, 64);
            acc[i] += __shfl_xor(acc[i], 16, 64);
            acc[i] += __shfl_xor(acc[i], 32, 64);
        }
        // lane (kc) writes (r = kc&3, bh = kc>>2); static select
        float myv = acc[0];
#pragma unroll
        for (int j = 1; j < 8; j++)
            if (kc == j) myv = acc[(j & 3) * 2 + (j >> 2)];
        gsm[(w * 4 + (kc & 3)) * 17 + (kc >> 2) * 8 + b_l] = myv;
        __syncthreads();

        // ---- activations + state update + packed h store (relaxed agent) ----
        if (tid < 128) {
            const int u  = tid & 7;
            const int bb = tid >> 3;
            float g0 = gsm[(0 * 8 + u) * 17 + bb] + bs0;
            float g1 = gsm[(1 * 8 + u) * 17 + bb] + bs1;
            float g2 = gsm[(2 * 8 + u) * 17 + bb] + bs2;
            float g3 = gsm[(3 * 8 + u) * 17 + bb] + bs3;
            float i_ = 1.0f / (1.0f + expf(-g0));
            float f_ = 1.0f / (1.0f + expf(-g1));
            float o_ = 1.0f / (1.0f + expf(-g3));
            float cn = f_ * cs_l[u * 16 + bb] + i_ * tanhf(g2);
            float hn = o_ * tanhf(cn);
            cs_l[u * 16 + bb] = cn;
            __hip_atomic_store(
                &hp[(((size_t)t * 4 + bgr) * 64 + rg) * 128 + tid],
                hn, __ATOMIC_RELAXED, __HIP_MEMORY_SCOPE_AGENT);
        }
        __syncthreads();   // every wave drains vmcnt before barrier: h at LLC

        if (t + 1 < SS) {
            // ---- publish our flag (data already at LLC) ----
            if (tid == 0)
                __hip_atomic_store(&flags[((size_t)t * 4 + bgr) * 64 + rg], 1u,
                                   __ATOMIC_RELAXED, __HIP_MEMORY_SCOPE_AGENT);

            // ---- ih(t+1) overlapped with the wait window ----
#pragma unroll
            for (int i = 0; i < 8; i++) acc_ih[i] = 0.0f;
#pragma unroll
            for (int bh = 0; bh < 2; bh++) {
                int xv = x[(t + 1) * BB + bgr * 16 + bh * 8 + b_l];
                const float* erow = emb + (size_t)xv * EE;
                for (int c = 0; c < 8; c++) {
                    const int k0 = c * 32 + kc * 4;
                    float4 e4 = *(const float4*)(erow + k0);
                    e4.x *= 16.0f; e4.y *= 16.0f; e4.z *= 16.0f; e4.w *= 16.0f;
#pragma unroll
                    for (int r = 0; r < 4; r++) {
                        float4 w4 = *(const float4*)(Wih + (size_t)grow[r] * EE + k0);
                        acc_ih[r * 2 + bh] += w4.x * e4.x + w4.y * e4.y +
                                              w4.z * e4.z + w4.w * e4.w;
                    }
                }
            }

            // ---- wave0 polls the 64-flag line for (t, bgr) ----
            if (w == 0) {
                const unsigned* fl = flags + ((size_t)t * 4 + bgr) * 64;
                for (;;) {
                    unsigned v = __hip_atomic_load(&fl[L], __ATOMIC_RELAXED,
                                                   __HIP_MEMORY_SCOPE_AGENT);
                    if (__all(v != 0u)) break;
                }
            }
            __syncthreads();

            // ---- stage h_t: 64 rg-blocks -> h_l[bh][b_l][k] ----
            const float* hsrc = hp + ((size_t)t * 4 + bgr) * 64 * 128;
#pragma unroll
            for (int i = 0; i < 16; i++) {
                int idx = i * 512 + tid;        // rg2*128 + bb*8 + u
                float v = __hip_atomic_load(&hsrc[idx], __ATOMIC_RELAXED,
                                            __HIP_MEMORY_SCOPE_AGENT);
                int bb = (idx >> 3) & 15, u = idx & 7, rg2 = idx >> 7;
                h_l[(bb >> 3) * 4160 + (bb & 7) * 520 + rg2 * 8 + u] = v;
            }
            __syncthreads();
        }
    }
}

// one wave per (t,b): logits = h @ W_out^T + b_out, then log_softmax
__global__ __launch_bounds__(256) void emis_kernel(
    const float* __restrict__ Wout, const float* __restrict__ bout,
    float* __restrict__ ws)
{
    int wid = blockIdx.x * 4 + (threadIdx.x >> 6);  // t*64 + b
    int L   = threadIdx.x & 63;
    int t = wid >> 6, b = wid & 63;
    const float* hb = ws + ((size_t)t * 4 + (b >> 4)) * 64 * 128;
    float hv[8];
#pragma unroll
    for (int i = 0; i < 8; i++)   // k = i*64 + L: rg = i*8 + (L>>3), u = L&7
        hv[i] = hb[(size_t)(i * 8 + (L >> 3)) * 128 + (b & 15) * 8 + (L & 7)];
    float acc[9];
#pragma unroll
    for (int tg = 0; tg < 9; tg++) acc[tg] = 0.0f;
    for (int i = 0; i < 8; i++) {
#pragma unroll
        for (int tg = 0; tg < 9; tg++)
            acc[tg] += Wout[tg * HH + i * 64 + L] * hv[i];
    }
#pragma unroll
    for (int tg = 0; tg < 9; tg++) {
        acc[tg] += __shfl_xor(acc[tg], 1, 64);
        acc[tg] += __shfl_xor(acc[tg], 2, 64);
        acc[tg] += __shfl_xor(acc[tg], 4, 64);
        acc[tg] += __shfl_xor(acc[tg], 8, 64);
        acc[tg] += __shfl_xor(acc[tg], 16, 64);
        acc[tg] += __shfl_xor(acc[tg], 32, 64);
    }
    float lg[9];
#pragma unroll
    for (int tg = 0; tg < 9; tg++) lg[tg] = acc[tg] + bout[tg];
    float m = lg[0];
#pragma unroll
    for (int tg = 1; tg < 9; tg++) m = fmaxf(m, lg[tg]);
    float ssum = 0.0f;
#pragma unroll
    for (int tg = 0; tg < 9; tg++) ssum += expf(lg[tg] - m);
    float lse = m + logf(ssum);
    float myo = lg[0] - lse;
#pragma unroll
    for (int tg = 1; tg < 9; tg++) if (L == tg) myo = lg[tg] - lse;
    if (L < 9) ws[EM_OFF + (size_t)wid * 9 + L] = myo;
}

// merged CRF: blocks 0..7 numerator, 8..15 forward(logZ), 16..23 viterbi
__global__ __launch_bounds__(512) void crf_all(
    const int* __restrict__ x, const int* __restrict__ bio,
    const float* __restrict__ start_t, const float* __restrict__ end_t,
    const float* __restrict__ trans, float* __restrict__ ws,
    float* __restrict__ out)
{
    const float* em = ws + EM_OFF;
    const int role  = blockIdx.x >> 3;
    const int local = blockIdx.x & 7;
    const int tid   = threadIdx.x;

    __shared__ float sc[9][8];
    __shared__ unsigned char hist[SS - 1][8][9];

    if (role == 0) {
        int b = local * 8 + (tid >> 6);
        int L = tid & 63;
        float sum = 0.0f;
        int cntm = 0;
#pragma unroll
        for (int j = 0; j < 8; j++) {
            int s = j * 64 + L;
            int tg = bio[s * BB + b];
            bool mk = (x[s * BB + b] != 0);
            cntm += mk ? 1 : 0;
            if (s == 0) {
                sum += start_t[tg] + em[(size_t)b * 9 + tg];
            } else if (mk) {
                int tp = bio[(s - 1) * BB + b];
                sum += em[((size_t)s * BB + b) * 9 + tg] + trans[tp * 9 + tg];
            }
        }
#pragma unroll
        for (int d = 1; d < 64; d <<= 1) {
            sum += __shfl_xor(sum, d, 64);
            cntm += __shfl_xor(cntm, d, 64);
        }
        if (L == 0) {
            int se = cntm - 1;
            sum += end_t[bio[se * BB + b]];
            ws[NUM_OFF + b] = sum;
        }
        return;
    }

    const int b_l = tid & 7;
    const int j   = tid >> 3;          // active j < 9
    const int b   = local * 8 + b_l;
    float tc[9];
    if (j < 9) {
#pragma unroll
        for (int i = 0; i < 9; i++) tc[i] = trans[i * 9 + j];
        sc[j][b_l] = start_t[j] + em[(size_t)b * 9 + j];
    }
    __syncthreads();

    if (role == 1) {
        for (int s = 1; s < SS; s++) {
            float nv = 0.0f;
            if (j < 9) {
                float sv[9];
                float m = -3.4e38f;
#pragma unroll
                for (int i = 0; i < 9; i++) {
                    sv[i] = sc[i][b_l] + tc[i];
                    m = fmaxf(m, sv[i]);
                }
                float ssum = 0.0f;
#pragma unroll
                for (int i = 0; i < 9; i++) ssum += expf(sv[i] - m);
                nv = m + logf(ssum) + em[((size_t)s * BB + b) * 9 + j];
            }
            bool mk = (x[s * BB + b] != 0);
            __syncthreads();
            if (j < 9 && mk) sc[j][b_l] = nv;
            __syncthreads();
        }
        if (j == 0) {
            float m = -3.4e38f;
#pragma unroll
            for (int i = 0; i < 9; i++) m = fmaxf(m, sc[i][b_l] + end_t[i]);
            float ssum = 0.0f;
#pragma unroll
            for (int i = 0; i < 9; i++) ssum += expf(sc[i][b_l] + end_t[i] - m);
            ws[NORM_OFF + b] = m + logf(ssum);
        }
    } else {
        for (int s = 1; s < SS; s++) {
            float nv = 0.0f;
            if (j < 9) {
                float best = sc[0][b_l] + tc[0];
                int bi = 0;
#pragma unroll
                for (int i = 1; i < 9; i++) {
                    float v = sc[i][b_l] + tc[i];
                    if (v > best) { best = v; bi = i; }  // first-max = jnp.argmax
                }
                hist[s - 1][b_l][j] = (unsigned char)bi;
                nv = best + em[((size_t)s * BB + b) * 9 + j];
            }
            __syncthreads();
            if (j < 9) sc[j][b_l] = nv;
            __syncthreads();
        }
        if (tid < 8) {
            int bl = tid;
            int gb = local * 8 + bl;
            float best = sc[0][bl] + end_t[0];
            int cur = 0;
#pragma unroll
            for (int i = 1; i < 9; i++) {
                float v = sc[i][bl] + end_t[i];
                if (v > best) { best = v; cur = i; }
            }
            out[1 + (size_t)(SS - 1) * BB + gb] = (float)cur;
            for (int s = SS - 2; s >= 0; s--) {
                cur = hist[s][bl][cur];
                out[1 + (size_t)s * BB + gb] = (float)cur;
            }
        }
    }
}

__global__ __launch_bounds__(64) void final_llh(const float* __restrict__ ws,
                                               float* __restrict__ out)
{
    int L = threadIdx.x;
    float v = ws[NUM_OFF + L] - ws[NORM_OFF + L];
    v += __shfl_xor(v, 1, 64);
    v += __shfl_xor(v, 2, 64);
    v += __shfl_xor(v, 4, 64);
    v += __shfl_xor(v, 8, 64);
    v += __shfl_xor(v, 16, 64);
    v += __shfl_xor(v, 32, 64);
    if (L == 0) out[0] = -v;
}

extern "C" void kernel_launch(void* const* d_in, const int* in_sizes, int n_in,
                              void* d_out, int out_size, void* d_ws, size_t ws_size,
                              hipStream_t stream) {
    const int*   x       = (const int*)d_in[0];
    const int*   bio     = (const int*)d_in[1];
    const float* emb     = (const float*)d_in[2];
    const float* W_ih    = (const float*)d_in[3];
    const float* W_hh    = (const float*)d_in[4];
    const float* b_ih    = (const float*)d_in[5];
    const float* b_hh    = (const float*)d_in[6];
    const float* W_out   = (const float*)d_in[7];
    const float* b_out   = (const float*)d_in[8];
    const float* start_t = (const float*)d_in[9];
    const float* end_t   = (const float*)d_in[10];
    const float* trans   = (const float*)d_in[11];
    float* out = (float*)d_out;
    float* ws  = (float*)d_ws;

    const size_t dyn_lds = (size_t)L_TOT * sizeof(float);   // 101504 B
    hipFuncSetAttribute((const void*)lstm_persistent,
                        hipFuncAttributeMaxDynamicSharedMemorySize,
                        (int)dyn_lds);

    init_flags<<<512, 256, 0, stream>>>(ws);
    lstm_persistent<<<NWG, 512, dyn_lds, stream>>>(W_hh, W_ih, b_ih, b_hh, emb, x, ws);
    emis_kernel<<<SS * BB / 4, 256, 0, stream>>>(W_out, b_out, ws);
    crf_all<<<24, 512, 0, stream>>>(x, bio, start_t, end_t, trans, ws, out);
    final_llh<<<1, 64, 0, stream>>>(ws, out);
}

// Round 10
// 6284.257 us; speedup vs baseline: 2.8125x; 1.8484x over previous
//
#include <hip/hip_runtime.h>
#include <math.h>

#define SS 512
#define BB 64
#define EE 256
#define HH 512
#define NT 9
#define NWG 256

// ws layout (float32 elements):
//  hs   : SS*BB*HH at 0        (hs[t] = h_t)
//  em   : SS*BB*NT at EM_OFF
//  num  : 64 at NUM_OFF
//  norm : 64 at NORM_OFF
//  flags: SS*8*32 u32 at FLAG_OFF   (flag per (t, bg, slice); 128B line per (t,bg))
#define HS_ELEMS ((size_t)SS * BB * HH)
#define EM_OFF   HS_ELEMS
#define NUM_OFF  (EM_OFF + (size_t)SS * BB * NT)
#define NORM_OFF (NUM_OFF + 64)
#define FLAG_OFF (NORM_OFF + 64)
#define FLAG_U32S ((size_t)SS * 8 * 32)

// dynamic LDS layout (floats)
#define L_WHH 0            // 64 rows x 512       = 32768 floats (128 KB)
#define L_H   32768        // 8 x 520             = 4160
#define L_GSM 36928        // 64 x 9              = 576
#define L_CS  37504        // 16 x 8              = 128
#define L_TOT 37632        // 150528 bytes

__global__ __launch_bounds__(256) void init_flags(float* __restrict__ ws) {
    unsigned* f = (unsigned*)(ws + FLAG_OFF);
    size_t idx = (size_t)blockIdx.x * 256 + threadIdx.x;
    if (idx < FLAG_U32S) f[idx] = 0u;
}

// Persistent LSTM: 256 WGs x 512 threads, one step per flag-barrier round.
// WG (slice = wg&31, bg = wg>>5): units slice*16..+16, batches bg*8..+8.
// Wave w: local gate-rows w*8..w*8+7 (row l = gate*16 + unit_local).
// Lane L: b_l = L&7, kc = L>>3.
// Whh lives in LDS (staged once). Cross-WG h via RELAXED agent atomics.
// Barrier v2 (only delta vs the 6.1ms R4 kernel): producers store one flag
// per (t,bg,slice) -- NO atomic-RMW chain -- and ALL waves poll the 32-flag
// line directly (no tid0-spin + syncthreads broadcast hop).
__global__ __launch_bounds__(512) void lstm_persistent(
    const float* __restrict__ Whh, const float* __restrict__ Wih,
    const float* __restrict__ bih, const float* __restrict__ bhh,
    const float* __restrict__ emb, const int* __restrict__ x,
    float* __restrict__ ws)
{
    const int wg    = blockIdx.x;
    const int slice = wg & 31;
    const int bg    = wg >> 5;
    const int tid   = threadIdx.x;
    const int w     = tid >> 6;
    const int L     = tid & 63;
    const int b_l   = L & 7;
    const int kc    = L >> 3;
    const int b     = bg * 8 + b_l;

    float* hs = ws;
    unsigned* flags = (unsigned*)(ws + FLAG_OFF);

    extern __shared__ float smem[];
    float* whh_l = smem + L_WHH;   // [l][512], l = local gate-row
    float* h_l   = smem + L_H;     // [b_l][520]
    float* gsm   = smem + L_GSM;   // [64][9]
    float* cs_l  = smem + L_CS;    // [u][8]

    int grow[8];
#pragma unroll
    for (int r = 0; r < 8; r++) {
        int l = w * 8 + r;
        grow[r] = (l >> 4) * HH + slice * 16 + (l & 15);
    }

    // ---- stage Whh slice (64 rows x 512) into LDS, coalesced ----
    for (int j = 0; j < 64; j++) {
        int idx = j * 512 + tid;          // l*512 + k
        int l = idx >> 9;
        int k = idx & 511;
        int gr = (l >> 4) * HH + slice * 16 + (l & 15);
        whh_l[idx] = Whh[(size_t)gr * HH + k];
    }

    // bias preload (activation threads only)
    float bs0 = 0.f, bs1 = 0.f, bs2 = 0.f, bs3 = 0.f;
    if (tid < 128) {
        const int u  = tid & 15;
        const int bb = tid >> 4;
        const int gu = slice * 16 + u;
        bs0 = bih[0 * HH + gu] + bhh[0 * HH + gu];
        bs1 = bih[1 * HH + gu] + bhh[1 * HH + gu];
        bs2 = bih[2 * HH + gu] + bhh[2 * HH + gu];
        bs3 = bih[3 * HH + gu] + bhh[3 * HH + gu];
        cs_l[u * 8 + bb] = 0.0f;
    }

    // h_{-1} = 0 locally
#pragma unroll
    for (int j = 0; j < 8; j++) {
        int idx = j * 512 + tid;
        h_l[(idx >> 9) * 520 + (idx & 511)] = 0.0f;
    }

    // ih-gates for t=0
    float acc_ih[8];
    {
        const int xv = x[0 * BB + b];
        const float* erow = emb + (size_t)xv * EE;
#pragma unroll
        for (int r = 0; r < 8; r++) acc_ih[r] = 0.0f;
        for (int c = 0; c < 8; c++) {
            const int k0 = c * 32 + kc * 4;
            float4 e4 = *(const float4*)(erow + k0);
            e4.x *= 16.0f; e4.y *= 16.0f; e4.z *= 16.0f; e4.w *= 16.0f;
#pragma unroll
            for (int r = 0; r < 8; r++) {
                float4 w4 = *(const float4*)(Wih + (size_t)grow[r] * EE + k0);
                acc_ih[r] += w4.x * e4.x + w4.y * e4.y + w4.z * e4.z + w4.w * e4.w;
            }
        }
    }
    __syncthreads();

    const float* wbase = whh_l + (size_t)(w * 8) * 512;

    for (int t = 0; t < SS; t++) {
        // ---- hh gates (Whh from LDS) ----
        float acc[8];
#pragma unroll
        for (int r = 0; r < 8; r++) acc[r] = acc_ih[r];
        const float* hrow = h_l + b_l * 520;
        for (int c = 0; c < 16; c++) {
            const int k0 = c * 32 + kc * 4;
            float4 h4 = *(const float4*)(hrow + k0);
#pragma unroll
            for (int r = 0; r < 8; r++) {
                float4 w4 = *(const float4*)(wbase + r * 512 + k0);
                acc[r] += w4.x * h4.x + w4.y * h4.y + w4.z * h4.z + w4.w * h4.w;
            }
        }

        // reduce over 8 kc-lanes
#pragma unroll
        for (int r = 0; r < 8; r++) {
            acc[r] += __shfl_xor(acc[r], 8, 64);
            acc[r] += __shfl_xor(acc[r], 16, 64);
            acc[r] += __shfl_xor(acc[r], 32, 64);
        }
        float myv = acc[0];
#pragma unroll
        for (int r = 1; r < 8; r++) if (kc == r) myv = acc[r];
        gsm[(w * 8 + kc) * 9 + b_l] = myv;
        __syncthreads();

        // ---- activations + state update + h_t store (relaxed agent) ----
        if (tid < 128) {
            const int u  = tid & 15;
            const int bb = tid >> 4;
            const int gu = slice * 16 + u;
            float gi = gsm[(0 * 16 + u) * 9 + bb] + bs0;
            float gf = gsm[(1 * 16 + u) * 9 + bb] + bs1;
            float gg = gsm[(2 * 16 + u) * 9 + bb] + bs2;
            float go = gsm[(3 * 16 + u) * 9 + bb] + bs3;
            float i_ = 1.0f / (1.0f + expf(-gi));
            float f_ = 1.0f / (1.0f + expf(-gf));
            float o_ = 1.0f / (1.0f + expf(-go));
            const int gb = bg * 8 + bb;
            float cn = f_ * cs_l[u * 8 + bb] + i_ * tanhf(gg);
            float hn = o_ * tanhf(cn);
            cs_l[u * 8 + bb] = cn;
            __hip_atomic_store(&hs[(size_t)t * BB * HH + (size_t)gb * HH + gu],
                               hn, __ATOMIC_RELAXED, __HIP_MEMORY_SCOPE_AGENT);
        }
        __syncthreads();   // each wave drains vmcnt before barrier: h at LLC

        if (t + 1 < SS) {
            // ---- publish our slice's flag (data already at LLC) ----
            if (tid == 0)
                __hip_atomic_store(&flags[((size_t)t * 8 + bg) * 32 + slice], 1u,
                                   __ATOMIC_RELAXED, __HIP_MEMORY_SCOPE_AGENT);

            // ---- ih(t+1) overlapped with the wait window ----
            {
                const int xv = x[(t + 1) * BB + b];
                const float* erow = emb + (size_t)xv * EE;
#pragma unroll
                for (int r = 0; r < 8; r++) acc_ih[r] = 0.0f;
                for (int c = 0; c < 8; c++) {
                    const int k0 = c * 32 + kc * 4;
                    float4 e4 = *(const float4*)(erow + k0);
                    e4.x *= 16.0f; e4.y *= 16.0f; e4.z *= 16.0f; e4.w *= 16.0f;
#pragma unroll
                    for (int r = 0; r < 8; r++) {
                        float4 w4 = *(const float4*)(Wih + (size_t)grow[r] * EE + k0);
                        acc_ih[r] += w4.x * e4.x + w4.y * e4.y + w4.z * e4.z + w4.w * e4.w;
                    }
                }
            }

            // ---- ALL waves poll the 32-flag line for (t, bg) ----
            {
                const unsigned* fl = flags + ((size_t)t * 8 + bg) * 32;
                for (;;) {
                    unsigned v = 1u;
                    if (L < 32)
                        v = __hip_atomic_load(&fl[L], __ATOMIC_RELAXED,
                                              __HIP_MEMORY_SCOPE_AGENT);
                    if (__all(v != 0u)) break;
                }
            }

            // ---- stage h_t into LDS (relaxed agent loads from LLC) ----
            const float* hsrc = hs + (size_t)t * BB * HH + (size_t)bg * 8 * HH;
#pragma unroll
            for (int j = 0; j < 8; j++) {
                int idx = j * 512 + tid;
                float v = __hip_atomic_load(&hsrc[idx], __ATOMIC_RELAXED,
                                            __HIP_MEMORY_SCOPE_AGENT);
                h_l[(idx >> 9) * 520 + (idx & 511)] = v;
            }
            __syncthreads();
        }
    }
}

// one wave per (t,b): logits = h @ W_out^T + b_out, then log_softmax
__global__ __launch_bounds__(256) void emis_kernel(
    const float* __restrict__ Wout, const float* __restrict__ bout,
    float* __restrict__ ws)
{
    int wid = blockIdx.x * 4 + (threadIdx.x >> 6);  // t*64 + b
    int L   = threadIdx.x & 63;
    const float* h = ws + (size_t)wid * HH;
    float hv[8];
#pragma unroll
    for (int i = 0; i < 8; i++) hv[i] = h[i * 64 + L];
    float acc[9];
#pragma unroll
    for (int tg = 0; tg < 9; tg++) acc[tg] = 0.0f;
    for (int i = 0; i < 8; i++) {
#pragma unroll
        for (int tg = 0; tg < 9; tg++)
            acc[tg] += Wout[tg * HH + i * 64 + L] * hv[i];
    }
#pragma unroll
    for (int tg = 0; tg < 9; tg++) {
        acc[tg] += __shfl_xor(acc[tg], 1, 64);
        acc[tg] += __shfl_xor(acc[tg], 2, 64);
        acc[tg] += __shfl_xor(acc[tg], 4, 64);
        acc[tg] += __shfl_xor(acc[tg], 8, 64);
        acc[tg] += __shfl_xor(acc[tg], 16, 64);
        acc[tg] += __shfl_xor(acc[tg], 32, 64);
    }
    float lg[9];
#pragma unroll
    for (int tg = 0; tg < 9; tg++) lg[tg] = acc[tg] + bout[tg];
    float m = lg[0];
#pragma unroll
    for (int tg = 1; tg < 9; tg++) m = fmaxf(m, lg[tg]);
    float ssum = 0.0f;
#pragma unroll
    for (int tg = 0; tg < 9; tg++) ssum += expf(lg[tg] - m);
    float lse = m + logf(ssum);
    float myo = lg[0] - lse;
#pragma unroll
    for (int tg = 1; tg < 9; tg++) if (L == tg) myo = lg[tg] - lse;
    if (L < 9) ws[EM_OFF + (size_t)wid * 9 + L] = myo;
}

// merged CRF: blocks 0..7 numerator, 8..15 forward(logZ), 16..23 viterbi
__global__ __launch_bounds__(512) void crf_all(
    const int* __restrict__ x, const int* __restrict__ bio,
    const float* __restrict__ start_t, const float* __restrict__ end_t,
    const float* __restrict__ trans, float* __restrict__ ws,
    float* __restrict__ out)
{
    const float* em = ws + EM_OFF;
    const int role  = blockIdx.x >> 3;
    const int local = blockIdx.x & 7;
    const int tid   = threadIdx.x;

    __shared__ float sc[9][8];
    __shared__ unsigned char hist[SS - 1][8][9];

    if (role == 0) {
        int b = local * 8 + (tid >> 6);
        int L = tid & 63;
        float sum = 0.0f;
        int cntm = 0;
#pragma unroll
        for (int j = 0; j < 8; j++) {
            int s = j * 64 + L;
            int tg = bio[s * BB + b];
            bool mk = (x[s * BB + b] != 0);
            cntm += mk ? 1 : 0;
            if (s == 0) {
                sum += start_t[tg] + em[(size_t)b * 9 + tg];
            } else if (mk) {
                int tp = bio[(s - 1) * BB + b];
                sum += em[((size_t)s * BB + b) * 9 + tg] + trans[tp * 9 + tg];
            }
        }
#pragma unroll
        for (int d = 1; d < 64; d <<= 1) {
            sum += __shfl_xor(sum, d, 64);
            cntm += __shfl_xor(cntm, d, 64);
        }
        if (L == 0) {
            int se = cntm - 1;
            sum += end_t[bio[se * BB + b]];
            ws[NUM_OFF + b] = sum;
        }
        return;
    }

    const int b_l = tid & 7;
    const int j   = tid >> 3;          // active j < 9
    const int b   = local * 8 + b_l;
    float tc[9];
    if (j < 9) {
#pragma unroll
        for (int i = 0; i < 9; i++) tc[i] = trans[i * 9 + j];
        sc[j][b_l] = start_t[j] + em[(size_t)b * 9 + j];
    }
    __syncthreads();

    if (role == 1) {
        for (int s = 1; s < SS; s++) {
            float nv = 0.0f;
            if (j < 9) {
                float sv[9];
                float m = -3.4e38f;
#pragma unroll
                for (int i = 0; i < 9; i++) {
                    sv[i] = sc[i][b_l] + tc[i];
                    m = fmaxf(m, sv[i]);
                }
                float ssum = 0.0f;
#pragma unroll
                for (int i = 0; i < 9; i++) ssum += expf(sv[i] - m);
                nv = m + logf(ssum) + em[((size_t)s * BB + b) * 9 + j];
            }
            bool mk = (x[s * BB + b] != 0);
            __syncthreads();
            if (j < 9 && mk) sc[j][b_l] = nv;
            __syncthreads();
        }
        if (j == 0) {
            float m = -3.4e38f;
#pragma unroll
            for (int i = 0; i < 9; i++) m = fmaxf(m, sc[i][b_l] + end_t[i]);
            float ssum = 0.0f;
#pragma unroll
            for (int i = 0; i < 9; i++) ssum += expf(sc[i][b_l] + end_t[i] - m);
            ws[NORM_OFF + b] = m + logf(ssum);
        }
    } else {
        for (int s = 1; s < SS; s++) {
            float nv = 0.0f;
            if (j < 9) {
                float best = sc[0][b_l] + tc[0];
                int bi = 0;
#pragma unroll
                for (int i = 1; i < 9; i++) {
                    float v = sc[i][b_l] + tc[i];
                    if (v > best) { best = v; bi = i; }  // first-max = jnp.argmax
                }
                hist[s - 1][b_l][j] = (unsigned char)bi;
                nv = best + em[((size_t)s * BB + b) * 9 + j];
            }
            __syncthreads();
            if (j < 9) sc[j][b_l] = nv;
            __syncthreads();
        }
        if (tid < 8) {
            int bl = tid;
            int gb = local * 8 + bl;
            float best = sc[0][bl] + end_t[0];
            int cur = 0;
#pragma unroll
            for (int i = 1; i < 9; i++) {
                float v = sc[i][bl] + end_t[i];
                if (v > best) { best = v; cur = i; }
            }
            out[1 + (size_t)(SS - 1) * BB + gb] = (float)cur;
            for (int s = SS - 2; s >= 0; s--) {
                cur = hist[s][bl][cur];
                out[1 + (size_t)s * BB + gb] = (float)cur;
            }
        }
    }
}

__global__ __launch_bounds__(64) void final_llh(const float* __restrict__ ws,
                                               float* __restrict__ out)
{
    int L = threadIdx.x;
    float v = ws[NUM_OFF + L] - ws[NORM_OFF + L];
    v += __shfl_xor(v, 1, 64);
    v += __shfl_xor(v, 2, 64);
    v += __shfl_xor(v, 4, 64);
    v += __shfl_xor(v, 8, 64);
    v += __shfl_xor(v, 16, 64);
    v += __shfl_xor(v, 32, 64);
    if (L == 0) out[0] = -v;
}

extern "C" void kernel_launch(void* const* d_in, const int* in_sizes, int n_in,
                              void* d_out, int out_size, void* d_ws, size_t ws_size,
                              hipStream_t stream) {
    const int*   x       = (const int*)d_in[0];
    const int*   bio     = (const int*)d_in[1];
    const float* emb     = (const float*)d_in[2];
    const float* W_ih    = (const float*)d_in[3];
    const float* W_hh    = (const float*)d_in[4];
    const float* b_ih    = (const float*)d_in[5];
    const float* b_hh    = (const float*)d_in[6];
    const float* W_out   = (const float*)d_in[7];
    const float* b_out   = (const float*)d_in[8];
    const float* start_t = (const float*)d_in[9];
    const float* end_t   = (const float*)d_in[10];
    const float* trans   = (const float*)d_in[11];
    float* out = (float*)d_out;
    float* ws  = (float*)d_ws;

    const size_t dyn_lds = (size_t)L_TOT * sizeof(float);   // 150528 B
    hipFuncSetAttribute((const void*)lstm_persistent,
                        hipFuncAttributeMaxDynamicSharedMemorySize,
                        (int)dyn_lds);

    init_flags<<<512, 256, 0, stream>>>(ws);
    lstm_persistent<<<NWG, 512, dyn_lds, stream>>>(W_hh, W_ih, b_ih, b_hh, emb, x, ws);
    emis_kernel<<<SS * BB / 4, 256, 0, stream>>>(W_out, b_out, ws);
    crf_all<<<24, 512, 0, stream>>>(x, bio, start_t, end_t, trans, ws, out);
    final_llh<<<1, 64, 0, stream>>>(ws, out);
}